// Round 1
// baseline (64.927 us; speedup 1.0000x reference)
//
#include <hip/hip_runtime.h>

// TropConv2D: out[b,ho,wo,f] = max_k(patch_k + w[k,f]) - min_k(patch_k + w[k,f])
// x: (8,32,32,32) f32 NHWC, w: (288,64) f32 (72 KB), out: (8,30,30,64) f32
// k = (i*3 + j)*32 + c   (TF extract_patches ordering)
//
// v6: scalar-pipe patch broadcast. v5 was LDS-return-BW bound: broadcast
//   ds_read_b128 writes 1 KB/instr into RFs (64 lanes x 16B replicated);
//   72 reads/wave x 7680 waves = 553 MB LDS traffic ~= 8+ us of LDS-pipe
//   time vs a 3.4 us VALU floor. Patch values are wave-uniform -> deliver
//   them via s_load_dwordx4 (16B total, scalar cache) and consume as the
//   SGPR operand of v_add_f32. Eliminates LDS staging, barrier #1, and all
//   broadcast ds_reads; SMEM traffic is ~8.8 MB total.
//   - SMEM completes out-of-order -> only lgkmcnt(0) is safe; pipeline is
//     wait(cur) -> issue ij+1 loads -> compute ij (latency under VALU+TLP).
//   - Consumers tied to the waitcnt via "+s" operands (rule-#18 hazard:
//     data-dep prevents hoisting compute above the wait).
//   - q=3 would read cols 32..33 OOB from global; clamp the scalar column
//     offset (coff) to col 31 -- clamped px>=6 are discarded at combine.
//   - Weight prefetch (VMEM, per-lane) and 8-wave channel-split combine
//     unchanged from v5 (max/min associative -> exact, absmax 0).

#define C_IN 32
#define NF 64
#define H_OUT 30
#define W_OUT 30
#define W_IN 32

typedef __attribute__((ext_vector_type(4))) float f32x4;

static __device__ __forceinline__ float max3f(float a, float b, float c) {
    return fmaxf(fmaxf(a, b), c);
}
static __device__ __forceinline__ float min3f(float a, float b, float c) {
    return fminf(fminf(a, b), c);
}

// scalar 16B load: base (SGPR pair) + byte offset (SGPR)
static __device__ __forceinline__ f32x4 sload16(const float* base, unsigned off_bytes) {
    f32x4 r;
    asm volatile("s_load_dwordx4 %0, %1, %2"
                 : "=s"(r)
                 : "s"(base), "s"(off_bytes));
    return r;
}

__global__ __launch_bounds__(512) void tropconv_kernel(
    const float* __restrict__ x,
    const float* __restrict__ w,
    float* __restrict__ out) {
    const int bx = blockIdx.x;            // 0..959
    const int q = bx & 3;                 // row quarter
    const int bho = bx >> 2;              // b*30 + ho
    const int b = bho / H_OUT;
    const int ho = bho - b * H_OUT;
    const int tid = threadIdx.x;
    const int lane = tid & 63;            // filter index
    // force wave-uniformity so all patch address math stays on the scalar pipe
    const int wave = __builtin_amdgcn_readfirstlane(tid >> 6);  // channel slice

    const int col0 = q * 8;
    const int npx = (q == 3) ? 6 : 8;

    __shared__ float pmx[8][8][NF];       // 16 KB partial max
    __shared__ float pmn[8][8][NF];       // 16 KB partial min

    // scalar patch base: row (b*32+ho), col 0, channel slice wave*4 (16B aligned)
    const float* sbase = x + ((size_t)(b * 32 + ho) * W_IN) * C_IN + wave * 4;

    // column byte offsets, clamped so q==3 never reads past col 31 (the
    // clamped loads feed px>=npx which the combine discards)
    const int mcc = 31 - col0;            // >= 9 for q<3, == 7 for q==3
    unsigned coff[10];
    #pragma unroll
    for (int c = 0; c < 10; ++c) {
        const int cc = (c < mcc) ? c : mcc;
        coff[c] = (unsigned)((col0 + cc) * C_IN * 4);
    }

    // weight base for this wave's channel slice: w[(ij*32 + wave*4 + cc)*64 + lane]
    const float* __restrict__ wbase = w + (size_t)(wave * 4) * NF + lane;

    float wc[4];                           // current ij weights (prefetched)
    #pragma unroll
    for (int cc = 0; cc < 4; ++cc) wc[cc] = wbase[cc * NF];

    // issue ij=0 patch loads (i=0, j=0 -> cols 0..7)
    f32x4 cur[8], nxt[8];
    #pragma unroll
    for (int px = 0; px < 8; ++px) cur[px] = sload16(sbase, coff[px]);

    float mx[8], mn[8];
    #pragma unroll
    for (int t = 0; t < 8; ++t) { mx[t] = -INFINITY; mn[t] = INFINITY; }

    #pragma unroll
    for (int ij = 0; ij < 9; ++ij) {
        // wait for this ij's scalar loads. SMEM returns out-of-order ->
        // only lgkmcnt(0) is safe, so the wait comes BEFORE issuing ij+1.
        // "+s" ties make the compute below data-dependent on the wait.
        asm volatile("s_waitcnt lgkmcnt(0)"
                     : "+s"(cur[0]), "+s"(cur[1]), "+s"(cur[2]), "+s"(cur[3]),
                       "+s"(cur[4]), "+s"(cur[5]), "+s"(cur[6]), "+s"(cur[7]));

        // issue next ij's patch loads (latency hidden behind this ij's VALU)
        if (ij < 8) {
            const int i1 = (ij + 1) / 3;
            const int j1 = (ij + 1) - i1 * 3;
            const unsigned rowoff = (unsigned)(i1 * W_IN * C_IN * 4);
            #pragma unroll
            for (int px = 0; px < 8; ++px)
                nxt[px] = sload16(sbase, rowoff + coff[j1 + px]);
        }

        // prefetch next ij's weights (VMEM, hidden behind this ij's compute)
        float wn[4];
        if (ij < 8) {
            #pragma unroll
            for (int cc = 0; cc < 4; ++cc)
                wn[cc] = wbase[((ij + 1) * C_IN + cc) * NF];
        }

        // compute: per px, 4x v_add_f32 (SGPR patch + VGPR weight) + 2 max3 + 2 min3
        #pragma unroll
        for (int px = 0; px < 8; ++px) {
            const f32x4 p = cur[px];
            float s0 = p.x + wc[0];
            float s1 = p.y + wc[1];
            float s2 = p.z + wc[2];
            float s3 = p.w + wc[3];
            mx[px] = max3f(max3f(s0, s1, s2), s3, mx[px]);
            mn[px] = min3f(min3f(s0, s1, s2), s3, mn[px]);
        }

        if (ij < 8) {
            #pragma unroll
            for (int px = 0; px < 8; ++px) cur[px] = nxt[px];
            #pragma unroll
            for (int cc = 0; cc < 4; ++cc) wc[cc] = wn[cc];
        }
    }

    #pragma unroll
    for (int px = 0; px < 8; ++px) {
        pmx[wave][px][lane] = mx[px];
        pmn[wave][px][lane] = mn[px];
    }
    __syncthreads();

    // ---- Cross-wave combine (exact: max/min associative) ----
    const int nout = npx * NF;            // 512 or 384
    if (tid < nout) {
        const int px = tid >> 6;
        const int f = tid & 63;
        float a = fmaxf(fmaxf(fmaxf(pmx[0][px][f], pmx[1][px][f]),
                              fmaxf(pmx[2][px][f], pmx[3][px][f])),
                        fmaxf(fmaxf(pmx[4][px][f], pmx[5][px][f]),
                              fmaxf(pmx[6][px][f], pmx[7][px][f])));
        float m = fminf(fminf(fminf(pmn[0][px][f], pmn[1][px][f]),
                              fminf(pmn[2][px][f], pmn[3][px][f])),
                        fminf(fminf(pmn[4][px][f], pmn[5][px][f]),
                              fminf(pmn[6][px][f], pmn[7][px][f])));
        out[((size_t)bho * W_OUT + (col0 + px)) * NF + f] = a - m;
    }
}

extern "C" void kernel_launch(void* const* d_in, const int* in_sizes, int n_in,
                              void* d_out, int out_size, void* d_ws, size_t ws_size,
                              hipStream_t stream) {
    const float* x = (const float*)d_in[0];   // 8*32*32*32
    const float* w = (const float*)d_in[1];   // 288*64
    float* out = (float*)d_out;               // 8*30*30*64

    dim3 grid(8 * H_OUT * 4);                 // 960 blocks
    dim3 block(512);
    tropconv_kernel<<<grid, block, 0, stream>>>(x, w, out);
}